// Round 2
// baseline (519.220 us; speedup 1.0000x reference)
//
#include <hip/hip_runtime.h>

// Problem constants (reference): B=64, N=256, S=16, HID=32, HEADS=8
#define NN 256
#define SS 16
#define HH 32
#define KK 8      // heads
#define NROWPAIRS 16384            // B*N (b,n) pairs
#define STATS_BLOCKS 2048
#define CPB 4                      // chunks per block in mlp kernel
#define MLP_BLOCKS (NROWPAIRS / CPB)   // 4096

// ---- workspace layout (bytes) ----
// 0   : int countRows   (# valid (b,n) pairs)      \
// 64  : float sx[16]                                > zeroed by one 192-B memsetAsync
// 128 : float sx2[16]                              /
// 192 : uchar valid[16384]

// ---------------------------------------------------------------------------
// Kernel 1: fused mask-dtype detect + valid[] + masked per-channel stats.
// Each block redundantly scans the first 16 KB of the mask (L2-broadcast,
// ~free) so no separate serial prep kernel is needed. Block bid owns chunks
// {bid + k*2048 : k=0..7}; one (b,n) chunk = 256 rows x 16 floats = 16 KB.
// ---------------------------------------------------------------------------
__global__ __launch_bounds__(256) void stats_kernel(
        const void* __restrict__ mask_raw,
        const float* __restrict__ stacks,
        unsigned char* __restrict__ valid,
        int* __restrict__ count_out,
        float* __restrict__ sx, float* __restrict__ sx2) {
    int tid = threadIdx.x;
    int bid = blockIdx.x;

    __shared__ int s_flags[2];   // [0]=float pattern, [1]=bool pattern
    __shared__ int s_mode;
    __shared__ int s_count;
    __shared__ unsigned char s_valid[8];
    if (tid < 2) s_flags[tid] = 0;
    if (tid == 0) s_count = 0;
    __syncthreads();

    // Scan first 16384 bytes as 4096 words (in-bounds for all 3 layouts:
    // bool[16384]=16KB exactly, int/float = 64KB).
    const unsigned int* w = (const unsigned int*)mask_raw;
    int f_float = 0, f_bool = 0;
    for (int i = tid; i < 4096; i += 256) {
        unsigned int v = w[i];
        if (v == 0x3F800000u) f_float = 1;
        // byte value 1 in a non-LSB position can only be packed bool bytes
        if (((v >> 8) & 0xFFu) == 1u || ((v >> 16) & 0xFFu) == 1u ||
            ((v >> 24) & 0xFFu) == 1u) f_bool = 1;
    }
    if (f_float) atomicOr(&s_flags[0], 1);
    if (f_bool)  atomicOr(&s_flags[1], 1);
    __syncthreads();
    if (tid == 0) s_mode = s_flags[1] ? 1 : (s_flags[0] ? 2 : 0);
    __syncthreads();
    int mode = s_mode;

    // valid bytes for this block's 8 chunks
    if (tid < 8) {
        int chunk = bid + tid * STATS_BLOCKS;
        int masked;
        if (mode == 1)      masked = ((const unsigned char*)mask_raw)[chunk] != 0;
        else if (mode == 2) masked = ((const float*)mask_raw)[chunk] != 0.0f;
        else                masked = ((const int*)mask_raw)[chunk] != 0;
        unsigned char v = (unsigned char)(masked ? 0 : 1);  // valid = !mask
        s_valid[tid] = v;
        valid[chunk] = v;
        if (v) atomicAdd(&s_count, 1);
    }
    __syncthreads();
    if (tid == 0 && s_count) atomicAdd(count_out, s_count);

    // masked sum / sum-of-squares; thread's float4 covers s = 4*(tid%4)..+3
    float4 s1 = make_float4(0.f, 0.f, 0.f, 0.f);
    float4 s2 = make_float4(0.f, 0.f, 0.f, 0.f);
    for (int k = 0; k < 8; ++k) {
        if (!s_valid[k]) continue;                 // block-uniform branch
        int chunk = bid + k * STATS_BLOCKS;
        const float4* p = (const float4*)stacks + (size_t)chunk * 1024;
        #pragma unroll
        for (int it = 0; it < 4; ++it) {
            float4 v = p[tid + it * 256];
            s1.x += v.x; s1.y += v.y; s1.z += v.z; s1.w += v.w;
            s2.x += v.x * v.x; s2.y += v.y * v.y;
            s2.z += v.z * v.z; s2.w += v.w * v.w;
        }
    }

    __shared__ float lds[8 * 256];   // [comp][tid]
    lds[0 * 256 + tid] = s1.x; lds[1 * 256 + tid] = s1.y;
    lds[2 * 256 + tid] = s1.z; lds[3 * 256 + tid] = s1.w;
    lds[4 * 256 + tid] = s2.x; lds[5 * 256 + tid] = s2.y;
    lds[6 * 256 + tid] = s2.z; lds[7 * 256 + tid] = s2.w;
    __syncthreads();

    if (tid < 32) {
        int kind = tid >> 4;          // 0 = sum, 1 = sum sq
        int s = tid & 15;
        int g = s >> 2, c = (s & 3) + kind * 4;
        float tot = 0.f;
        for (int i = 0; i < 64; ++i) tot += lds[c * 256 + (g + i * 4)];
        atomicAdd(kind ? &sx2[s] : &sx[s], tot);
    }
}

// ---------------------------------------------------------------------------
// Kernel 2: fused BN-fold + per-row MLP. Each block stages the folded
// weights once in LDS (computing scale/shift/W1c/b1c from the raw params +
// stats — replaces the old weights_kernel), then processes CPB=4 chunks.
// Blocks run in REVERSE chunk order so the second read of `stacks` hits the
// 256 MiB Infinity Cache where the stats pass just left it (268 MB total).
// Thread = one m row: 16 floats in, 8 floats out. Accumulation order is
// identical to the previous version (k-outer/j-inner, then j-outer/i-inner).
// ---------------------------------------------------------------------------
__global__ __launch_bounds__(256) void mlp_kernel(
        const float* __restrict__ stacks,
        const unsigned char* __restrict__ valid,
        const float* __restrict__ gamma,
        const float* __restrict__ beta,
        const float* __restrict__ W1,
        const float* __restrict__ b1,
        const float* __restrict__ W2,
        const float* __restrict__ b2,
        const float* __restrict__ sx,
        const float* __restrict__ sx2,
        const int* __restrict__ count_rows,
        float* __restrict__ out) {
    int tid = threadIdx.x;
    int bid = (MLP_BLOCKS - 1) - (int)blockIdx.x;   // reverse for L3 reuse

    // LDS weights: [0..511] W1c [16][32], [512..543] b1c,
    //              [544..799] W2 [32][8], [800..807] b2
    __shared__ __align__(16) float w_s[808];
    __shared__ float s_scale[SS], s_shift[SS];

    // ---- phase 1: BN scale/shift (t<16) + stage W2,b2 (no deps) ----
    if (tid < SS) {
        float cnt = (float)(*count_rows) * (float)NN;
        if (cnt < 1.0f) cnt = 1.0f;
        float mean = sx[tid] / cnt;
        float var  = sx2[tid] / cnt - mean * mean;
        float sc   = gamma[tid] / sqrtf(var + 1e-5f);
        s_scale[tid] = sc;
        s_shift[tid] = beta[tid] - mean * sc;
    } else if (tid >= 128 && tid < 192) {
        ((float4*)&w_s[544])[tid - 128] = ((const float4*)W2)[tid - 128];
    } else if (tid >= 192 && tid < 194) {
        ((float4*)&w_s[800])[tid - 192] = ((const float4*)b2)[tid - 192];
    }
    __syncthreads();

    // ---- phase 2: W1c = scale (.) W1 (t<128), b1c = shift@W1 + b1 (t>=224)
    if (tid < 128) {
        float4 wv = ((const float4*)W1)[tid];
        float sc = s_scale[tid >> 3];      // 8 float4 per s-row of 32
        wv.x *= sc; wv.y *= sc; wv.z *= sc; wv.w *= sc;
        ((float4*)&w_s[0])[tid] = wv;
    } else if (tid >= 224) {
        int j = tid - 224;
        float acc = b1[j];
        #pragma unroll
        for (int s = 0; s < SS; ++s) acc += s_shift[s] * W1[s * HH + j];
        w_s[512 + j] = acc;
    }
    __syncthreads();

    const float4* W1v = (const float4*)&w_s[0];     // [16][8] float4
    const float4* b1v = (const float4*)&w_s[512];   // 8 float4
    const float4* W2v = (const float4*)&w_s[544];   // [32][2] float4
    const float4* b2v = (const float4*)&w_s[800];   // 2 float4

    for (int c = 0; c < CPB; ++c) {
        int chunk = bid * CPB + c;
        size_t row = (size_t)chunk * NN + tid;
        float4* outp = (float4*)out + row * 2;

        if (!valid[chunk]) {               // block-uniform branch
            float4 z = make_float4(0.f, 0.f, 0.f, 0.f);
            outp[0] = z; outp[1] = z;
            continue;
        }

        const float4* xp = (const float4*)stacks + row * 4;
        float4 x0 = xp[0], x1 = xp[1], x2 = xp[2], x3 = xp[3];
        float x[SS] = { x0.x, x0.y, x0.z, x0.w,  x1.x, x1.y, x1.z, x1.w,
                        x2.x, x2.y, x2.z, x2.w,  x3.x, x3.y, x3.z, x3.w };

        // layer 1: h = x @ W1c + b1c  (k-outer, j-inner)
        float4 h[8];
        #pragma unroll
        for (int jv = 0; jv < 8; ++jv) h[jv] = b1v[jv];
        #pragma unroll
        for (int k = 0; k < SS; ++k) {
            float xk = x[k];
            #pragma unroll
            for (int jv = 0; jv < 8; ++jv) {
                float4 wv = W1v[k * 8 + jv];     // broadcast ds_read_b128
                h[jv].x = fmaf(xk, wv.x, h[jv].x);
                h[jv].y = fmaf(xk, wv.y, h[jv].y);
                h[jv].z = fmaf(xk, wv.z, h[jv].z);
                h[jv].w = fmaf(xk, wv.w, h[jv].w);
            }
        }
        float hs[HH];
        #pragma unroll
        for (int jv = 0; jv < 8; ++jv) {
            hs[4 * jv + 0] = fmaxf(h[jv].x, 0.0f);
            hs[4 * jv + 1] = fmaxf(h[jv].y, 0.0f);
            hs[4 * jv + 2] = fmaxf(h[jv].z, 0.0f);
            hs[4 * jv + 3] = fmaxf(h[jv].w, 0.0f);
        }

        // layer 2: y = h @ W2 + b2  (j-outer, i-inner)
        float4 y0 = b2v[0], y1 = b2v[1];
        #pragma unroll
        for (int j = 0; j < HH; ++j) {
            float hj = hs[j];
            float4 wa = W2v[j * 2 + 0];
            float4 wb = W2v[j * 2 + 1];
            y0.x = fmaf(hj, wa.x, y0.x);
            y0.y = fmaf(hj, wa.y, y0.y);
            y0.z = fmaf(hj, wa.z, y0.z);
            y0.w = fmaf(hj, wa.w, y0.w);
            y1.x = fmaf(hj, wb.x, y1.x);
            y1.y = fmaf(hj, wb.y, y1.y);
            y1.z = fmaf(hj, wb.z, y1.z);
            y1.w = fmaf(hj, wb.w, y1.w);
        }

        outp[0] = y0;
        outp[1] = y1;
    }
}

extern "C" void kernel_launch(void* const* d_in, const int* in_sizes, int n_in,
                              void* d_out, int out_size, void* d_ws, size_t ws_size,
                              hipStream_t stream) {
    const float* stacks = (const float*)d_in[0];
    const void*  mask   = d_in[1];
    const float* gamma  = (const float*)d_in[2];
    const float* beta   = (const float*)d_in[3];
    const float* W1     = (const float*)d_in[4];
    const float* b1     = (const float*)d_in[5];
    const float* W2     = (const float*)d_in[6];
    const float* b2     = (const float*)d_in[7];
    float* out = (float*)d_out;

    char* ws = (char*)d_ws;
    int*           countRows = (int*)(ws + 0);
    float*         sx        = (float*)(ws + 64);
    float*         sx2       = (float*)(ws + 128);
    unsigned char* valid     = (unsigned char*)(ws + 192);

    // zero count + sx + sx2 (ws is poisoned 0xAA before every launch)
    hipMemsetAsync(ws, 0, 192, stream);

    stats_kernel<<<STATS_BLOCKS, 256, 0, stream>>>(mask, stacks, valid,
                                                   countRows, sx, sx2);
    mlp_kernel<<<MLP_BLOCKS, 256, 0, stream>>>(stacks, valid, gamma, beta,
                                               W1, b1, W2, b2, sx, sx2,
                                               countRows, out);
}

// Round 3
// 495.977 us; speedup vs baseline: 1.0469x; 1.0469x over previous
//
#include <hip/hip_runtime.h>

// Problem constants (reference): B=64, N=256, S=16, HID=32, HEADS=8
#define NN 256
#define SS 16
#define HH 32
#define KK 8      // heads
#define NROWPAIRS 16384            // B*N (b,n) pairs
#define STATS_BLOCKS 2048

// ---- workspace layout (bytes) ----
// 64    : uchar valid[16384]
// 16448 : int countPartial[2048]
// 24704 : float partials[2048][32]   (kind*16+s per block; 256 KB)
// 286848: float W1c[512]
// 288896: float b1c[32]
// No zeroing needed: all accumulators are written, never read-modify-written.

// ---------------------------------------------------------------------------
// Kernel 1: fused mask-dtype detect + valid[] + masked per-channel partial
// stats. Each block redundantly scans the first 16 KB of the mask region
// (L2-broadcast, ~1 us aggregate) -> no serial prep kernel. Block bid owns
// chunks {bid + k*2048 : k=0..7}; one (b,n) chunk = 256 rows x 16 ch = 16 KB.
// Partial sums go to partials[bid][0..31] (no atomics, no pre-zeroing).
// ---------------------------------------------------------------------------
__global__ __launch_bounds__(256) void stats_kernel(
        const void* __restrict__ mask_raw,
        const float* __restrict__ stacks,
        unsigned char* __restrict__ valid,
        int* __restrict__ count_partial,
        float* __restrict__ partials) {
    int tid = threadIdx.x;
    int bid = blockIdx.x;

    __shared__ int s_flags[2];   // [0]=float pattern, [1]=bool pattern
    __shared__ int s_mode;
    __shared__ int s_count;
    __shared__ unsigned char s_valid[8];
    if (tid < 2) s_flags[tid] = 0;
    if (tid == 0) s_count = 0;
    __syncthreads();

    // Scan first 16384 bytes as 4096 words (in-bounds for all 3 layouts:
    // bool[16384] = 16KB exactly; int/float = 64KB).
    const unsigned int* w = (const unsigned int*)mask_raw;
    int f_float = 0, f_bool = 0;
    for (int i = tid; i < 4096; i += 256) {
        unsigned int v = w[i];
        if (v == 0x3F800000u) f_float = 1;
        // byte value 1 in a non-LSB position can only be packed bool bytes
        if (((v >> 8) & 0xFFu) == 1u || ((v >> 16) & 0xFFu) == 1u ||
            ((v >> 24) & 0xFFu) == 1u) f_bool = 1;
    }
    if (f_float) atomicOr(&s_flags[0], 1);
    if (f_bool)  atomicOr(&s_flags[1], 1);
    __syncthreads();
    if (tid == 0) s_mode = s_flags[1] ? 1 : (s_flags[0] ? 2 : 0);
    __syncthreads();
    int mode = s_mode;

    // valid bytes for this block's 8 chunks
    if (tid < 8) {
        int chunk = bid + tid * STATS_BLOCKS;
        int masked;
        if (mode == 1)      masked = ((const unsigned char*)mask_raw)[chunk] != 0;
        else if (mode == 2) masked = ((const float*)mask_raw)[chunk] != 0.0f;
        else                masked = ((const int*)mask_raw)[chunk] != 0;
        unsigned char v = (unsigned char)(masked ? 0 : 1);  // valid = !mask
        s_valid[tid] = v;
        valid[chunk] = v;
        if (v) atomicAdd(&s_count, 1);
    }
    __syncthreads();

    // masked sum / sum-of-squares; thread's float4 covers s = 4*(tid%4)..+3
    float4 s1 = make_float4(0.f, 0.f, 0.f, 0.f);
    float4 s2 = make_float4(0.f, 0.f, 0.f, 0.f);
    for (int k = 0; k < 8; ++k) {
        if (!s_valid[k]) continue;                 // block-uniform branch
        int chunk = bid + k * STATS_BLOCKS;
        const float4* p = (const float4*)stacks + (size_t)chunk * 1024;
        #pragma unroll
        for (int it = 0; it < 4; ++it) {
            float4 v = p[tid + it * 256];
            s1.x += v.x; s1.y += v.y; s1.z += v.z; s1.w += v.w;
            s2.x += v.x * v.x; s2.y += v.y * v.y;
            s2.z += v.z * v.z; s2.w += v.w * v.w;
        }
    }

    __shared__ float lds[8 * 256];   // [comp][tid]
    lds[0 * 256 + tid] = s1.x; lds[1 * 256 + tid] = s1.y;
    lds[2 * 256 + tid] = s1.z; lds[3 * 256 + tid] = s1.w;
    lds[4 * 256 + tid] = s2.x; lds[5 * 256 + tid] = s2.y;
    lds[6 * 256 + tid] = s2.z; lds[7 * 256 + tid] = s2.w;
    __syncthreads();

    if (tid < 32) {
        int kind = tid >> 4;          // 0 = sum, 1 = sum sq
        int s = tid & 15;
        int g = s >> 2, c = (s & 3) + kind * 4;
        float tot = 0.f;
        for (int i = 0; i < 64; ++i) tot += lds[c * 256 + (g + i * 4)];
        partials[bid * 32 + tid] = tot;          // plain store, no atomic
    }
    if (tid == 0) count_partial[bid] = s_count;
}

// ---------------------------------------------------------------------------
// Kernel 2: reduce the 2048 partials + counts, fold BN into layer 1.
// scale = gamma/sqrt(var+eps); shift = beta - mean*scale;
// W1c = scale (.) W1;  b1c = shift @ W1 + b1.   One block, 512 threads.
// ---------------------------------------------------------------------------
__global__ __launch_bounds__(512) void weights_kernel(
        const float* __restrict__ gamma,
        const float* __restrict__ beta,
        const float* __restrict__ W1,
        const float* __restrict__ b1,
        const float* __restrict__ partials,
        const int* __restrict__ count_partial,
        float* __restrict__ W1c,
        float* __restrict__ b1c) {
    int tid = threadIdx.x;
    __shared__ float red[512];
    __shared__ int s_cnt;
    __shared__ float s_scale[SS], s_shift[SS];

    if (tid == 0) s_cnt = 0;

    // sum partials: output c = tid&31, strip j = tid>>5 (16 strips of 128)
    {
        int c = tid & 31, j = tid >> 5;
        float acc = 0.f;
        for (int k = j; k < STATS_BLOCKS; k += 16) acc += partials[k * 32 + c];
        red[tid] = acc;
    }
    // sum counts: 4 per thread
    int cacc = 0;
    for (int k = tid; k < STATS_BLOCKS; k += 512) cacc += count_partial[k];
    __syncthreads();
    if (tid < 256) red[tid] += red[tid + 256];
    if (cacc) atomicAdd(&s_cnt, cacc);
    __syncthreads();
    if (tid < 128) red[tid] += red[tid + 128];
    __syncthreads();
    if (tid < 64) red[tid] += red[tid + 64];
    __syncthreads();
    if (tid < 32) red[tid] += red[tid + 32];
    __syncthreads();
    // red[s] = sum_x[s], red[16+s] = sum_x2[s]

    if (tid < SS) {
        float cnt = (float)s_cnt * (float)NN;
        if (cnt < 1.0f) cnt = 1.0f;
        float mean = red[tid] / cnt;
        float var  = red[16 + tid] / cnt - mean * mean;
        float sc   = gamma[tid] / sqrtf(var + 1e-5f);
        s_scale[tid] = sc;
        s_shift[tid] = beta[tid] - mean * sc;
    }
    __syncthreads();
    W1c[tid] = s_scale[tid >> 5] * W1[tid];
    if (tid < HH) {
        float acc = b1[tid];
        #pragma unroll
        for (int s = 0; s < SS; ++s) acc += s_shift[s] * W1[s * HH + tid];
        b1c[tid] = acc;
    }
}

// ---------------------------------------------------------------------------
// Kernel 3: per-row fused MLP (R0 configuration — best measured). Block =
// one (b,n) pair (mask branch is block-uniform); thread = one m row.
// 16 floats in, 8 floats out. Weights via uniform global loads (L1-served).
// ---------------------------------------------------------------------------
__global__ __launch_bounds__(256) void mlp_kernel(
        const float* __restrict__ stacks,
        const unsigned char* __restrict__ valid,
        const float* __restrict__ W1c,
        const float* __restrict__ b1c,
        const float* __restrict__ W2,
        const float* __restrict__ b2,
        float* __restrict__ out) {
    int bid = blockIdx.x;
    int tid = threadIdx.x;
    size_t row = (size_t)bid * NN + tid;
    float4* outp = (float4*)out + row * 2;

    if (!valid[bid]) {
        float4 z = make_float4(0.f, 0.f, 0.f, 0.f);
        outp[0] = z; outp[1] = z;
        return;
    }

    const float4* xp = (const float4*)stacks + row * 4;
    float4 x0 = xp[0], x1 = xp[1], x2 = xp[2], x3 = xp[3];
    float x[SS] = { x0.x, x0.y, x0.z, x0.w,  x1.x, x1.y, x1.z, x1.w,
                    x2.x, x2.y, x2.z, x2.w,  x3.x, x3.y, x3.z, x3.w };

    float h[HH];
    #pragma unroll
    for (int j = 0; j < HH; ++j) h[j] = b1c[j];
    #pragma unroll
    for (int k = 0; k < SS; ++k) {
        float xk = x[k];
        #pragma unroll
        for (int j = 0; j < HH; ++j) h[j] = fmaf(xk, W1c[k * HH + j], h[j]);
    }
    #pragma unroll
    for (int j = 0; j < HH; ++j) h[j] = fmaxf(h[j], 0.0f);

    float y[KK];
    #pragma unroll
    for (int i = 0; i < KK; ++i) y[i] = b2[i];
    #pragma unroll
    for (int j = 0; j < HH; ++j) {
        float hj = h[j];
        #pragma unroll
        for (int i = 0; i < KK; ++i) y[i] = fmaf(hj, W2[j * KK + i], y[i]);
    }

    outp[0] = make_float4(y[0], y[1], y[2], y[3]);
    outp[1] = make_float4(y[4], y[5], y[6], y[7]);
}

extern "C" void kernel_launch(void* const* d_in, const int* in_sizes, int n_in,
                              void* d_out, int out_size, void* d_ws, size_t ws_size,
                              hipStream_t stream) {
    const float* stacks = (const float*)d_in[0];
    const void*  mask   = d_in[1];
    const float* gamma  = (const float*)d_in[2];
    const float* beta   = (const float*)d_in[3];
    const float* W1     = (const float*)d_in[4];
    const float* b1     = (const float*)d_in[5];
    const float* W2     = (const float*)d_in[6];
    const float* b2     = (const float*)d_in[7];
    float* out = (float*)d_out;

    char* ws = (char*)d_ws;
    unsigned char* valid        = (unsigned char*)(ws + 64);
    int*           countPartial = (int*)(ws + 16448);
    float*         partials     = (float*)(ws + 24704);
    float*         W1c          = (float*)(ws + 286848);
    float*         b1c          = (float*)(ws + 288896);

    stats_kernel<<<STATS_BLOCKS, 256, 0, stream>>>(mask, stacks, valid,
                                                   countPartial, partials);
    weights_kernel<<<1, 512, 0, stream>>>(gamma, beta, W1, b1,
                                          partials, countPartial, W1c, b1c);
    mlp_kernel<<<NROWPAIRS, 256, 0, stream>>>(stacks, valid, W1c, b1c,
                                              W2, b2, out);
}

// Round 5
// 495.444 us; speedup vs baseline: 1.0480x; 1.0011x over previous
//
#include <hip/hip_runtime.h>

// Problem constants (reference): B=64, N=256, S=16, HID=32, HEADS=8
#define NN 256
#define SS 16
#define HH 32
#define KK 8      // heads
#define NROWPAIRS 16384            // B*N (b,n) pairs
#define STATS_BLOCKS 2048

typedef float f32x4 __attribute__((ext_vector_type(4)));   // native vec for nt-store

// ---- workspace layout (bytes) ----
// 64    : uchar valid[16384]
// 16448 : int countPartial[2048]
// 24704 : float partials[2048][32]   (kind*16+s per block; 256 KB)
// 286848: float W1c[512]
// 288896: float b1c[32]
// No zeroing needed: all accumulators are written, never read-modify-written.

// ---------------------------------------------------------------------------
// Kernel 1: fused mask-dtype detect + valid[] + masked per-channel partial
// stats. Each block redundantly scans the first 16 KB of the mask region
// (L2-broadcast, ~1 us aggregate) -> no serial prep kernel. Block bid owns
// chunks {bid + k*2048 : k=0..7}; one (b,n) chunk = 256 rows x 16 ch = 16 KB.
// Partial sums go to partials[bid][0..31] (no atomics, no pre-zeroing).
// ---------------------------------------------------------------------------
__global__ __launch_bounds__(256) void stats_kernel(
        const void* __restrict__ mask_raw,
        const float* __restrict__ stacks,
        unsigned char* __restrict__ valid,
        int* __restrict__ count_partial,
        float* __restrict__ partials) {
    int tid = threadIdx.x;
    int bid = blockIdx.x;

    __shared__ int s_flags[2];   // [0]=float pattern, [1]=bool pattern
    __shared__ int s_mode;
    __shared__ int s_count;
    __shared__ unsigned char s_valid[8];
    if (tid < 2) s_flags[tid] = 0;
    if (tid == 0) s_count = 0;
    __syncthreads();

    // Scan first 16384 bytes as 4096 words (in-bounds for all 3 layouts:
    // bool[16384] = 16KB exactly; int/float = 64KB).
    const unsigned int* w = (const unsigned int*)mask_raw;
    int f_float = 0, f_bool = 0;
    for (int i = tid; i < 4096; i += 256) {
        unsigned int v = w[i];
        if (v == 0x3F800000u) f_float = 1;
        // byte value 1 in a non-LSB position can only be packed bool bytes
        if (((v >> 8) & 0xFFu) == 1u || ((v >> 16) & 0xFFu) == 1u ||
            ((v >> 24) & 0xFFu) == 1u) f_bool = 1;
    }
    if (f_float) atomicOr(&s_flags[0], 1);
    if (f_bool)  atomicOr(&s_flags[1], 1);
    __syncthreads();
    if (tid == 0) s_mode = s_flags[1] ? 1 : (s_flags[0] ? 2 : 0);
    __syncthreads();
    int mode = s_mode;

    // valid bytes for this block's 8 chunks
    if (tid < 8) {
        int chunk = bid + tid * STATS_BLOCKS;
        int masked;
        if (mode == 1)      masked = ((const unsigned char*)mask_raw)[chunk] != 0;
        else if (mode == 2) masked = ((const float*)mask_raw)[chunk] != 0.0f;
        else                masked = ((const int*)mask_raw)[chunk] != 0;
        unsigned char v = (unsigned char)(masked ? 0 : 1);  // valid = !mask
        s_valid[tid] = v;
        valid[chunk] = v;
        if (v) atomicAdd(&s_count, 1);
    }
    __syncthreads();

    // masked sum / sum-of-squares; thread's float4 covers s = 4*(tid%4)..+3
    float4 s1 = make_float4(0.f, 0.f, 0.f, 0.f);
    float4 s2 = make_float4(0.f, 0.f, 0.f, 0.f);
    for (int k = 0; k < 8; ++k) {
        if (!s_valid[k]) continue;                 // block-uniform branch
        int chunk = bid + k * STATS_BLOCKS;
        const float4* p = (const float4*)stacks + (size_t)chunk * 1024;
        #pragma unroll
        for (int it = 0; it < 4; ++it) {
            float4 v = p[tid + it * 256];
            s1.x += v.x; s1.y += v.y; s1.z += v.z; s1.w += v.w;
            s2.x += v.x * v.x; s2.y += v.y * v.y;
            s2.z += v.z * v.z; s2.w += v.w * v.w;
        }
    }

    __shared__ float lds[8 * 256];   // [comp][tid]
    lds[0 * 256 + tid] = s1.x; lds[1 * 256 + tid] = s1.y;
    lds[2 * 256 + tid] = s1.z; lds[3 * 256 + tid] = s1.w;
    lds[4 * 256 + tid] = s2.x; lds[5 * 256 + tid] = s2.y;
    lds[6 * 256 + tid] = s2.z; lds[7 * 256 + tid] = s2.w;
    __syncthreads();

    if (tid < 32) {
        int kind = tid >> 4;          // 0 = sum, 1 = sum sq
        int s = tid & 15;
        int g = s >> 2, c = (s & 3) + kind * 4;
        float tot = 0.f;
        for (int i = 0; i < 64; ++i) tot += lds[c * 256 + (g + i * 4)];
        partials[bid * 32 + tid] = tot;          // plain store, no atomic
    }
    if (tid == 0) count_partial[bid] = s_count;
}

// ---------------------------------------------------------------------------
// Kernel 2: reduce the 2048 partials + counts, fold BN into layer 1.
// scale = gamma/sqrt(var+eps); shift = beta - mean*scale;
// W1c = scale (.) W1;  b1c = shift @ W1 + b1.   One block, 512 threads.
// ---------------------------------------------------------------------------
__global__ __launch_bounds__(512) void weights_kernel(
        const float* __restrict__ gamma,
        const float* __restrict__ beta,
        const float* __restrict__ W1,
        const float* __restrict__ b1,
        const float* __restrict__ partials,
        const int* __restrict__ count_partial,
        float* __restrict__ W1c,
        float* __restrict__ b1c) {
    int tid = threadIdx.x;
    __shared__ float red[512];
    __shared__ int s_cnt;
    __shared__ float s_scale[SS], s_shift[SS];

    if (tid == 0) s_cnt = 0;

    // sum partials: output c = tid&31, strip j = tid>>5 (16 strips of 128)
    {
        int c = tid & 31, j = tid >> 5;
        float acc = 0.f;
        for (int k = j; k < STATS_BLOCKS; k += 16) acc += partials[k * 32 + c];
        red[tid] = acc;
    }
    // sum counts: 4 per thread
    int cacc = 0;
    for (int k = tid; k < STATS_BLOCKS; k += 512) cacc += count_partial[k];
    __syncthreads();
    if (tid < 256) red[tid] += red[tid + 256];
    if (cacc) atomicAdd(&s_cnt, cacc);
    __syncthreads();
    if (tid < 128) red[tid] += red[tid + 128];
    __syncthreads();
    if (tid < 64) red[tid] += red[tid + 64];
    __syncthreads();
    if (tid < 32) red[tid] += red[tid + 32];
    __syncthreads();
    // red[s] = sum_x[s], red[16+s] = sum_x2[s]

    if (tid < SS) {
        float cnt = (float)s_cnt * (float)NN;
        if (cnt < 1.0f) cnt = 1.0f;
        float mean = red[tid] / cnt;
        float var  = red[16 + tid] / cnt - mean * mean;
        float sc   = gamma[tid] / sqrtf(var + 1e-5f);
        s_scale[tid] = sc;
        s_shift[tid] = beta[tid] - mean * sc;
    }
    __syncthreads();
    W1c[tid] = s_scale[tid >> 5] * W1[tid];
    if (tid < HH) {
        float acc = b1[tid];
        #pragma unroll
        for (int s = 0; s < SS; ++s) acc += s_shift[s] * W1[s * HH + tid];
        b1c[tid] = acc;
    }
}

// ---------------------------------------------------------------------------
// Kernel 3: per-row fused MLP (R0/R3 configuration — best measured). Block =
// one (b,n) pair (mask branch is block-uniform); thread = one m row.
// 16 floats in, 8 floats out. Weights via uniform global loads (L1-served).
//
// v5: output stores are NONTEMPORAL (via native ext_vector float4 — the HIP
// float4 struct type is rejected by the builtin). `stacks` is exactly
// 256 MiB = the Infinity-Cache size; after the stats pass it is L3-resident.
// Plain output stores (134 MB stream) write-allocate in L3 and evict
// `stacks` ahead of our own re-read. The nt hint makes the write stream
// evict-first so the re-read stays L3-served.
// ---------------------------------------------------------------------------
__global__ __launch_bounds__(256) void mlp_kernel(
        const float* __restrict__ stacks,
        const unsigned char* __restrict__ valid,
        const float* __restrict__ W1c,
        const float* __restrict__ b1c,
        const float* __restrict__ W2,
        const float* __restrict__ b2,
        float* __restrict__ out) {
    int bid = blockIdx.x;
    int tid = threadIdx.x;
    size_t row = (size_t)bid * NN + tid;
    f32x4* outp = (f32x4*)out + row * 2;

    if (!valid[bid]) {
        f32x4 z = (f32x4){0.f, 0.f, 0.f, 0.f};
        __builtin_nontemporal_store(z, outp);
        __builtin_nontemporal_store(z, outp + 1);
        return;
    }

    const float4* xp = (const float4*)stacks + row * 4;
    float4 x0 = xp[0], x1 = xp[1], x2 = xp[2], x3 = xp[3];
    float x[SS] = { x0.x, x0.y, x0.z, x0.w,  x1.x, x1.y, x1.z, x1.w,
                    x2.x, x2.y, x2.z, x2.w,  x3.x, x3.y, x3.z, x3.w };

    float h[HH];
    #pragma unroll
    for (int j = 0; j < HH; ++j) h[j] = b1c[j];
    #pragma unroll
    for (int k = 0; k < SS; ++k) {
        float xk = x[k];
        #pragma unroll
        for (int j = 0; j < HH; ++j) h[j] = fmaf(xk, W1c[k * HH + j], h[j]);
    }
    #pragma unroll
    for (int j = 0; j < HH; ++j) h[j] = fmaxf(h[j], 0.0f);

    float y[KK];
    #pragma unroll
    for (int i = 0; i < KK; ++i) y[i] = b2[i];
    #pragma unroll
    for (int j = 0; j < HH; ++j) {
        float hj = h[j];
        #pragma unroll
        for (int i = 0; i < KK; ++i) y[i] = fmaf(hj, W2[j * KK + i], y[i]);
    }

    f32x4 y0 = (f32x4){y[0], y[1], y[2], y[3]};
    f32x4 y1 = (f32x4){y[4], y[5], y[6], y[7]};
    __builtin_nontemporal_store(y0, outp);
    __builtin_nontemporal_store(y1, outp + 1);
}

extern "C" void kernel_launch(void* const* d_in, const int* in_sizes, int n_in,
                              void* d_out, int out_size, void* d_ws, size_t ws_size,
                              hipStream_t stream) {
    const float* stacks = (const float*)d_in[0];
    const void*  mask   = d_in[1];
    const float* gamma  = (const float*)d_in[2];
    const float* beta   = (const float*)d_in[3];
    const float* W1     = (const float*)d_in[4];
    const float* b1     = (const float*)d_in[5];
    const float* W2     = (const float*)d_in[6];
    const float* b2     = (const float*)d_in[7];
    float* out = (float*)d_out;

    char* ws = (char*)d_ws;
    unsigned char* valid        = (unsigned char*)(ws + 64);
    int*           countPartial = (int*)(ws + 16448);
    float*         partials     = (float*)(ws + 24704);
    float*         W1c          = (float*)(ws + 286848);
    float*         b1c          = (float*)(ws + 288896);

    stats_kernel<<<STATS_BLOCKS, 256, 0, stream>>>(mask, stacks, valid,
                                                   countPartial, partials);
    weights_kernel<<<1, 512, 0, stream>>>(gamma, beta, W1, b1,
                                          partials, countPartial, W1c, b1c);
    mlp_kernel<<<NROWPAIRS, 256, 0, stream>>>(stacks, valid, W1c, b1c,
                                              W2, b2, out);
}